// Round 1
// baseline (332.815 us; speedup 1.0000x reference)
//
#include <hip/hip_runtime.h>

// Fused self-attention, B=32, H=W=64, C=256.
// One WAVE per (b,c) chain; block = 4 waves = 4 channels; grid = 2048 (cg-major).
//
// vs previous version:
//  * prep_w kernel pre-transposes Wq/Wk into bf16 MFMA A-fragment layout in d_ws
//    (4 MiB) -> main kernel loads weights as coalesced b128 global loads (L2-shared
//    across the 32 b-blocks of a channel group). Removes per-chain weight staging.
//  * q (M1->M3) and Sn (M3->M4) handoffs done fully in registers with
//    v_permlane32_swap + v_permlane16_swap (C-layout quad-4-chunks -> A-frag
//    quad-8-chunks is exactly a 32-swap followed by a 16-swap).
//  * K (M2->M3) keeps the LDS path but reuses the X buffer (free after xf load).
//  * All bf16 packing via v_cvt_pk_bf16_f32 (RNE, bit-identical to manual round).
//  * LDS: 32768 B/block (one 8 KiB buffer per wave: X -> K -> out).
//    __launch_bounds__(256,3) -> 3 blocks/CU (12 waves/CU) vs previous 2.

typedef short short8 __attribute__((ext_vector_type(8)));
typedef float floatx4 __attribute__((ext_vector_type(4)));
typedef unsigned int uint;

__device__ __forceinline__ uint cvtpk(float a, float b) {  // pack 2 bf16 (RNE)
  uint r;
  asm("v_cvt_pk_bf16_f32 %0, %1, %2" : "=v"(r) : "v"(a), "v"(b));
  return r;
}
__device__ __forceinline__ short8 u4s8(uint a, uint b, uint c, uint d) {
  union { uint u[4]; short8 s; } t;
  t.u[0] = a; t.u[1] = b; t.u[2] = c; t.u[3] = d;
  return t.s;
}
__device__ __forceinline__ float hsg(float x) {
  return fminf(fmaxf(0.2f * x + 0.5f, 0.f), 1.f);
}

// lo = [A_lanes0-31, C_lanes0-31], hi = [A_lanes32-63, C_lanes32-63]
__device__ __forceinline__ void pl32swap(uint A, uint C, uint& lo, uint& hi, int quad) {
#if __has_builtin(__builtin_amdgcn_permlane32_swap)
  auto r = __builtin_amdgcn_permlane32_swap(A, C, false, false);
  lo = (uint)r[0]; hi = (uint)r[1];
#else
  uint sA = __shfl_xor(A, 32), sC = __shfl_xor(C, 32);
  bool up = quad >= 2;
  lo = up ? sC : A;
  hi = up ? C : sA;
#endif
}
// rows = 16-lane groups: lo = [A_r0, C_r0, A_r2, C_r2], hi = [A_r1, C_r1, A_r3, C_r3]
__device__ __forceinline__ void pl16swap(uint A, uint C, uint& lo, uint& hi, int quad) {
#if __has_builtin(__builtin_amdgcn_permlane16_swap)
  auto r = __builtin_amdgcn_permlane16_swap(A, C, false, false);
  lo = (uint)r[0]; hi = (uint)r[1];
#else
  uint sA = (uint)__builtin_amdgcn_ds_swizzle((int)A, 0x401F);
  uint sC = (uint)__builtin_amdgcn_ds_swizzle((int)C, 0x401F);
  bool odd = quad & 1;
  lo = odd ? sC : A;
  hi = odd ? C : sA;
#endif
}
// C-layout words s[kt][r] (k-pair idx 8kt+2q+r) -> A-frag short8 (k-pair idx 16ks+4q+u)
__device__ __forceinline__ short8 xchg4(uint A, uint B, uint C, uint D, int quad) {
  uint Ap, Cp, Bp, Dp, t0, t1, t2, t3;
  pl32swap(A, C, Ap, Cp, quad);
  pl32swap(B, D, Bp, Dp, quad);
  pl16swap(Ap, Cp, t0, t2, quad);
  pl16swap(Bp, Dp, t1, t3, quad);
  return u4s8(t0, t1, t2, t3);
}

// ---- prep: Wq/Wk (C,64,64 f32) -> bf16 A-fragment layout in ws -------------
// task = mat*256 + c; per task 4096 u16: frag (kt,ks) at short8[(kt*2+ks)*64 + lane],
// element j = W[c][w = ks*32 + quad*8 + j][k = kt*16 + l15].
__global__ __launch_bounds__(256) void prep_w(const float* __restrict__ Wq,
                                              const float* __restrict__ Wk,
                                              unsigned short* __restrict__ ws) {
  __shared__ __align__(16) unsigned char sm[4 * 8704];
  const int tid = threadIdx.x, lane = tid & 63, wid = tid >> 6;
  const int task = blockIdx.x * 4 + wid;              // [0, 512)
  const int c = task & 255;
  const float* wp = ((task >> 8) ? Wk : Wq) + (size_t)c * 4096;
  unsigned char* buf = sm + wid * 8704;
  const int l15 = lane & 15, quad = lane >> 4;
#pragma unroll 4
  for (int j = 0; j < 16; ++j) {                      // stage [w][k], stride 136 B
    int f4 = j * 64 + lane;
    float4 v = *(const float4*)(wp + (size_t)f4 * 4);
    int w = f4 >> 4, k0 = (f4 & 15) << 2;
    uint2 pk; pk.x = cvtpk(v.x, v.y); pk.y = cvtpk(v.z, v.w);
    *(uint2*)(buf + w * 136 + k0 * 2) = pk;
  }
  unsigned short* dst = ws + (size_t)task * 4096;
#pragma unroll
  for (int kt = 0; kt < 4; ++kt)
#pragma unroll
    for (int ks = 0; ks < 2; ++ks) {                  // transposed u16 gather
      const unsigned short* p = (const unsigned short*)buf + (ks * 32 + quad * 8) * 68 + (kt * 16 + l15);
      short8 af = u4s8((uint)p[0]   | ((uint)p[68]  << 16),
                       (uint)p[136] | ((uint)p[204] << 16),
                       (uint)p[272] | ((uint)p[340] << 16),
                       (uint)p[408] | ((uint)p[476] << 16));
      *(short8*)(dst + ((kt * 2 + ks) * 64 + lane) * 8) = af;
    }
}

// ---- main ------------------------------------------------------------------
__global__ __launch_bounds__(256, 3) void fused_attn(
    const float* __restrict__ x, const unsigned short* __restrict__ wsp,
    float* __restrict__ out) {
  __shared__ __align__(16) unsigned char smem[4 * 8192];

  const int tid  = threadIdx.x;
  const int lane = tid & 63;
  const int wid  = tid >> 6;
  const int l15  = lane & 15;
  const int quad = lane >> 4;

  const int b  = blockIdx.x & 31;        // b inner: consecutive blocks share W[c]
  const int cg = blockIdx.x >> 5;
  const int c0 = cg << 2;
  const int c  = c0 + wid;

  unsigned char* buf0 = smem + wid * 8192;

  const short8* wqf = (const short8*)wsp + (size_t)c * 512;
  const short8* wkf = wqf + 256 * 512;

  // prefetch Wq fragments (hide under X staging + barrier)
  short8 aq[4][2];
#pragma unroll
  for (int kt = 0; kt < 4; ++kt)
#pragma unroll
    for (int ks = 0; ks < 2; ++ks) aq[kt][ks] = wqf[(kt * 2 + ks) * 64 + lane];

  // ---- Phase A: cooperative X staging, 2-w pairs -> b32 LDS stores ---------
  {
    const float* xb = x + (size_t)b * 4096 * 256 + c0;
#pragma unroll
    for (int i = 0; i < 8; ++i) {
      int p = i * 256 + tid;
      int h = p >> 5, w0 = (p & 31) << 1;
      const float* src = xb + (size_t)(h * 64 + w0) * 256;
      float4 v0 = *(const float4*)src;
      float4 v1 = *(const float4*)(src + 256);
      uint off = (uint)(h * 128 + (((w0 >> 3) ^ (h & 7)) << 4) + ((w0 & 7) << 1));
      uint pw0 = cvtpk(v0.x, v1.x), pw1 = cvtpk(v0.y, v1.y);
      uint pw2 = cvtpk(v0.z, v1.z), pw3 = cvtpk(v0.w, v1.w);
      *(uint*)(smem + 0 * 8192 + off) = pw0;
      *(uint*)(smem + 1 * 8192 + off) = pw1;
      *(uint*)(smem + 2 * 8192 + off) = pw2;
      *(uint*)(smem + 3 * 8192 + off) = pw3;
    }
  }
  __syncthreads();

  // ---- X fragments -> registers (B-operand layout); buf0 free afterwards ---
  short8 xf[4][2];
#pragma unroll
  for (int rt = 0; rt < 4; ++rt) {
    int r = rt * 16 + l15;
#pragma unroll
    for (int ks = 0; ks < 2; ++ks)
      xf[rt][ks] = *(const short8*)(buf0 + r * 128 + (((ks * 4 + quad) ^ (r & 7)) << 4));
  }

  const floatx4 zero4 = {0.f, 0.f, 0.f, 0.f};
  floatx4 acc[16];

  // ==== M1: qT = WqT x X (acc: k = kt*16+quad*4+i, h = ht*16+l15) ===========
#pragma unroll
  for (int i = 0; i < 16; ++i) acc[i] = zero4;
  __builtin_amdgcn_s_setprio(1);
#pragma unroll
  for (int kt = 0; kt < 4; ++kt)
#pragma unroll
    for (int ht = 0; ht < 4; ++ht) {
      acc[kt * 4 + ht] = __builtin_amdgcn_mfma_f32_16x16x32_bf16(aq[kt][0], xf[ht][0], acc[kt * 4 + ht], 0, 0, 0);
      acc[kt * 4 + ht] = __builtin_amdgcn_mfma_f32_16x16x32_bf16(aq[kt][1], xf[ht][1], acc[kt * 4 + ht], 0, 0, 0);
    }
  __builtin_amdgcn_s_setprio(0);

  // hard_sigmoid + in-register exchange -> qf[wt][ks] (A-frag: h=wt*16+l15)
  short8 qf[4][2];
#pragma unroll
  for (int ht = 0; ht < 4; ++ht) {
    uint s[4][2];
#pragma unroll
    for (int kt = 0; kt < 4; ++kt) {
      floatx4 a = acc[kt * 4 + ht];
      s[kt][0] = cvtpk(hsg(a[0]), hsg(a[1]));
      s[kt][1] = cvtpk(hsg(a[2]), hsg(a[3]));
    }
#pragma unroll
    for (int ks = 0; ks < 2; ++ks)
      qf[ht][ks] = xchg4(s[2 * ks][0], s[2 * ks][1], s[2 * ks + 1][0], s[2 * ks + 1][1], quad);
  }

  // ==== M2: KT = WkT x X; tanh; K[m][k] -> buf0 (overwrites X) ==============
#pragma unroll
  for (int i = 0; i < 16; ++i) acc[i] = zero4;
#pragma unroll
  for (int kt = 0; kt < 4; ++kt) {
    short8 a0 = wkf[(kt * 2 + 0) * 64 + lane];
    short8 a1 = wkf[(kt * 2 + 1) * 64 + lane];
    __builtin_amdgcn_s_setprio(1);
#pragma unroll
    for (int ht = 0; ht < 4; ++ht) {
      acc[kt * 4 + ht] = __builtin_amdgcn_mfma_f32_16x16x32_bf16(a0, xf[ht][0], acc[kt * 4 + ht], 0, 0, 0);
      acc[kt * 4 + ht] = __builtin_amdgcn_mfma_f32_16x16x32_bf16(a1, xf[ht][1], acc[kt * 4 + ht], 0, 0, 0);
    }
    __builtin_amdgcn_s_setprio(0);
  }
#pragma unroll
  for (int kt = 0; kt < 4; ++kt)
#pragma unroll
    for (int ht = 0; ht < 4; ++ht) {                  // lane: fixed m, 4 consecutive k
      floatx4 a = acc[kt * 4 + ht];
      float kv[4];
#pragma unroll
      for (int i = 0; i < 4; ++i) {
        float t = __expf(2.f * a[i]);
        kv[i] = 1.f - 2.f / (t + 1.f);                // tanh
      }
      uint2 pk; pk.x = cvtpk(kv[0], kv[1]); pk.y = cvtpk(kv[2], kv[3]);
      int m = ht * 16 + l15;
      *(uint2*)(buf0 + m * 128 + ((((kt * 2 + (quad >> 1)) ^ (m & 7))) << 4) + ((quad & 1) << 3)) = pk;
    }

  // ==== M3: S = q x K^T (acc: w = wt*16+quad*4+i, m = mt*16+l15) ============
#pragma unroll
  for (int i = 0; i < 16; ++i) acc[i] = zero4;
#pragma unroll
  for (int mt = 0; mt < 4; ++mt) {
    int r = mt * 16 + l15;
    short8 kf0 = *(const short8*)(buf0 + r * 128 + (((quad) ^ (r & 7)) << 4));
    short8 kf1 = *(const short8*)(buf0 + r * 128 + (((4 + quad) ^ (r & 7)) << 4));
    __builtin_amdgcn_s_setprio(1);
#pragma unroll
    for (int wt = 0; wt < 4; ++wt) {
      acc[wt * 4 + mt] = __builtin_amdgcn_mfma_f32_16x16x32_bf16(qf[wt][0], kf0, acc[wt * 4 + mt], 0, 0, 0);
      acc[wt * 4 + mt] = __builtin_amdgcn_mfma_f32_16x16x32_bf16(qf[wt][1], kf1, acc[wt * 4 + mt], 0, 0, 0);
    }
    __builtin_amdgcn_s_setprio(0);
  }
  // e = exp(hs(s)); hs in [0,1] -> no max subtraction needed
#pragma unroll
  for (int i = 0; i < 16; ++i)
#pragma unroll
    for (int j = 0; j < 4; ++j) acc[i][j] = __expf(hsg(acc[i][j]));
  float inv[4][4];
#pragma unroll
  for (int wt = 0; wt < 4; ++wt)
#pragma unroll
    for (int i = 0; i < 4; ++i) {                     // row sum: 3 adds + 4 shfls
      float p = acc[wt * 4 + 0][i] + acc[wt * 4 + 1][i] + acc[wt * 4 + 2][i] + acc[wt * 4 + 3][i];
      p += __shfl_xor(p, 1, 16);
      p += __shfl_xor(p, 2, 16);
      p += __shfl_xor(p, 4, 16);
      p += __shfl_xor(p, 8, 16);
      inv[wt][i] = 1.f / p;
    }
  // normalize + in-register exchange -> sf[mt][ks] (A-frag: m=mt*16+l15, k=w)
  short8 sf[4][2];
#pragma unroll
  for (int mt = 0; mt < 4; ++mt) {
    uint s[4][2];
#pragma unroll
    for (int wt = 0; wt < 4; ++wt) {
      floatx4 a = acc[wt * 4 + mt];
      s[wt][0] = cvtpk(a[0] * inv[wt][0], a[1] * inv[wt][1]);
      s[wt][1] = cvtpk(a[2] * inv[wt][2], a[3] * inv[wt][3]);
    }
#pragma unroll
    for (int ks = 0; ks < 2; ++ks)
      sf[mt][ks] = xchg4(s[2 * ks][0], s[2 * ks][1], s[2 * ks + 1][0], s[2 * ks + 1][1], quad);
  }

  // ==== M4: outT = SnT x X -> out[h][m] into buf0 (K fully consumed) ========
#pragma unroll
  for (int i = 0; i < 16; ++i) acc[i] = zero4;
  __builtin_amdgcn_s_setprio(1);
#pragma unroll
  for (int mt = 0; mt < 4; ++mt)
#pragma unroll
    for (int ht = 0; ht < 4; ++ht) {
      acc[mt * 4 + ht] = __builtin_amdgcn_mfma_f32_16x16x32_bf16(sf[mt][0], xf[ht][0], acc[mt * 4 + ht], 0, 0, 0);
      acc[mt * 4 + ht] = __builtin_amdgcn_mfma_f32_16x16x32_bf16(sf[mt][1], xf[ht][1], acc[mt * 4 + ht], 0, 0, 0);
    }
  __builtin_amdgcn_s_setprio(0);
#pragma unroll
  for (int mt = 0; mt < 4; ++mt)
#pragma unroll
    for (int ht = 0; ht < 4; ++ht) {                  // lane: fixed h, 4 consecutive m
      floatx4 a = acc[mt * 4 + ht];
      uint2 pk; pk.x = cvtpk(a[0], a[1]); pk.y = cvtpk(a[2], a[3]);
      int h = ht * 16 + l15;
      *(uint2*)(buf0 + h * 128 + ((((mt * 2 + (quad >> 1)) ^ (h & 7))) << 4) + ((quad & 1) << 3)) = pk;
    }
  __syncthreads();

  // ---- Phase C: cooperative output (b64 slot reads, float4 global stores) --
  const size_t outbase = (size_t)b * 4096 * 256 + c0;
#pragma unroll
  for (int rep = 0; rep < 4; ++rep) {
    int idx = rep * 256 + tid;
    int h = idx >> 4, mq = idx & 15;                  // m0 = mq*4
    uint loff = (uint)(h * 128 + ((((mq >> 1) ^ (h & 7))) << 4) + ((mq & 1) << 3));
    float vals[4][4];
#pragma unroll
    for (int j = 0; j < 4; ++j) {
      uint2 d = *(const uint2*)(smem + j * 8192 + loff);
      vals[j][0] = __uint_as_float(d.x << 16);
      vals[j][1] = __uint_as_float(d.x & 0xFFFF0000u);
      vals[j][2] = __uint_as_float(d.y << 16);
      vals[j][3] = __uint_as_float(d.y & 0xFFFF0000u);
    }
    float* op = out + outbase + (size_t)(h * 64 + mq * 4) * 256;
#pragma unroll
    for (int jj = 0; jj < 4; ++jj) {
      float4 v = {vals[0][jj], vals[1][jj], vals[2][jj], vals[3][jj]};
      *(float4*)(op + (size_t)jj * 256) = v;
    }
  }
}

extern "C" void kernel_launch(void* const* d_in, const int* in_sizes, int n_in,
                              void* d_out, int out_size, void* d_ws, size_t ws_size,
                              hipStream_t stream) {
  const float* x  = (const float*)d_in[0];
  const float* Wq = (const float*)d_in[1];
  const float* Wk = (const float*)d_in[2];
  unsigned short* ws = (unsigned short*)d_ws;  // 4 MiB used
  prep_w<<<dim3(128), dim3(256), 0, stream>>>(Wq, Wk, ws);
  fused_attn<<<dim3(2048), dim3(256), 0, stream>>>(x, ws, (float*)d_out);
}